// Round 5
// baseline (26.259 us; speedup 1.0000x reference)
//
#include <hip/hip_runtime.h>
#include <float.h>
#include <limits.h>

#define WAVE 64
#define CHUNKS 8

__device__ __forceinline__ void amax_upd(float v, int i, float& bv, int& bi) {
    if (v > bv || (v == bv && i < bi)) { bv = v; bi = i; }
}

// Block-wide argmax with first-index tie-break; result valid on thread 0.
template <int BLOCK>
__device__ __forceinline__ void block_argmax(float& bv, int& bi) {
#pragma unroll
    for (int off = 32; off > 0; off >>= 1) {
        float ov = __shfl_down(bv, off);
        int   oi = __shfl_down(bi, off);
        amax_upd(ov, oi, bv, bi);
    }
    __shared__ float sv[BLOCK / WAVE];
    __shared__ int   si[BLOCK / WAVE];
    int wid  = threadIdx.x / WAVE;
    int lane = threadIdx.x % WAVE;
    if (lane == 0) { sv[wid] = bv; si[wid] = bi; }
    __syncthreads();
    if (threadIdx.x == 0) {
        for (int w = 1; w < BLOCK / WAVE; ++w) amax_upd(sv[w], si[w], bv, bi);
    }
}

// is_greedy may be byte-packed bools or int32; detect from first
// min(B,16) words (64 bytes, in-bounds under both layouts). Uniform scalar.
__device__ __forceinline__ bool get_greedy(const void* isg_raw, int B, int b) {
    const unsigned* w = (const unsigned*)isg_raw;
    int nw = B < 16 ? B : 16;
    bool is_int = true;
    for (int i = 0; i < nw; ++i) if (w[i] > 1u) { is_int = false; break; }
    int v = is_int ? ((const int*)isg_raw)[b]
                   : (int)((const unsigned char*)isg_raw)[b];
    return v != 0;
}

// Request id for row i = count of cu[t] <= i, via wave ballot (1 coalesced
// load + popcount per 64 requests). All waves compute the same value.
__device__ __forceinline__ int find_req(const int* __restrict__ cu, int B, int i) {
    int b = 0;
    for (int base = 0; base < B; base += WAVE) {
        int t = base + (threadIdx.x & (WAVE - 1));
        int c = (t < B && cu[t] <= i) ? 1 : 0;
        unsigned long long m = __ballot(c);
        b += __popcll(m);
    }
    return b;
}

// Chunk [v0,v1) argmax of row (greedy) or of max(tp-dp,0)/q (recovery).
template <bool REC>
__device__ __forceinline__ void chunk_argmax(
    const float* __restrict__ tprow, const float* __restrict__ dprow,
    const float* __restrict__ qrow, int v0, int v1, float& bv, int& bi)
{
    int a0 = (v0 + 3) & ~3;
    int a1 = v1 & ~3;
    for (int v = v0 + (int)threadIdx.x; v < min(a0, v1); v += blockDim.x) {
        float x = REC ? fmaxf(tprow[v] - dprow[v], 0.0f) / qrow[v] : tprow[v];
        amax_upd(x, v, bv, bi);
    }
    if (a1 > a0) {
        const float4* t4 = (const float4*)(tprow + a0);
        const float4* d4 = (const float4*)(dprow + a0);
        const float4* q4 = (const float4*)(qrow  + a0);
        int np = (a1 - a0) >> 2;
        for (int p = threadIdx.x; p < np; p += blockDim.x) {
            float4 tv = t4[p];
            int base = a0 + (p << 2);
            if (REC) {
                float4 dv = d4[p], qv = q4[p];
                amax_upd(fmaxf(tv.x - dv.x, 0.0f) / qv.x, base,     bv, bi);
                amax_upd(fmaxf(tv.y - dv.y, 0.0f) / qv.y, base + 1, bv, bi);
                amax_upd(fmaxf(tv.z - dv.z, 0.0f) / qv.z, base + 2, bv, bi);
                amax_upd(fmaxf(tv.w - dv.w, 0.0f) / qv.w, base + 3, bv, bi);
            } else {
                amax_upd(tv.x, base,     bv, bi);
                amax_upd(tv.y, base + 1, bv, bi);
                amax_upd(tv.z, base + 2, bv, bi);
                amax_upd(tv.w, base + 3, bv, bi);
            }
        }
    }
    for (int v = max(a1, a0) + (int)threadIdx.x; v < v1; v += blockDim.x) {
        float x = REC ? fmaxf(tprow[v] - dprow[v], 0.0f) / qrow[v] : tprow[v];
        amax_upd(x, v, bv, bi);
    }
}

// K_main: block e*CHUNKS+c handles chunk c of entry e.
//   e in [0,B): recovery job for request e (non-greedy, first rejection).
//   e in [B,B+N): greedy argmax of tp row (e-B).
// Partials -> ws_pval/ws_pidx[e*CHUNKS+c]; valid only for active entries.
__global__ void __launch_bounds__(256) k_main(
    const float* __restrict__ tp, const float* __restrict__ dp,
    const float* __restrict__ q, const int* __restrict__ cu,
    const void* __restrict__ isg_raw, const int* __restrict__ draft_tok,
    const float* __restrict__ uni,
    float* __restrict__ ws_pval, int* __restrict__ ws_pidx,
    int B, int Sl, int V, int N)
{
    int e = blockIdx.x / CHUNKS;
    int c = blockIdx.x % CHUNKS;
    int tid = threadIdx.x;
    int v0 = (int)((long long)V * c / CHUNKS);
    int v1 = (int)((long long)V * (c + 1) / CHUNKS);
    float bv = -FLT_MAX; int bi = INT_MAX;

    if (e < B) {
        int b = e;
        if (get_greedy(isg_raw, B, b)) return;
        int st = b ? cu[b - 1] : 0;
        int np = cu[b] - st;
        int lim = min(np, Sl);
        __shared__ unsigned char s_acc[64];
        __shared__ int s_fr;
        if (tid < lim) {
            int g = min(max(st + tid, 0), N - 1);
            int t = draft_tok[g];
            float dpv = dp[(size_t)g * V + t];
            float tpv = tp[(size_t)g * V + t];
            s_acc[tid] = ((dpv > 0.0f) && (tpv / dpv >= uni[g])) ? 1 : 0;
        }
        __syncthreads();
        if (tid == 0) {
            int fr = Sl;
            for (int p = 0; p < lim; ++p)
                if (!s_acc[p]) { fr = p; break; }
            s_fr = fr;
        }
        __syncthreads();
        int fr = s_fr;
        if (fr >= lim) return;             // no recovery needed
        int g = min(max(st + fr, 0), N - 1);
        chunk_argmax<true>(tp + (size_t)g * V, dp + (size_t)g * V,
                           q + (size_t)b * V, v0, v1, bv, bi);
    } else {
        int i = e - B;
        int b = find_req(cu, B, i);
        if (b >= B || !get_greedy(isg_raw, B, b)) return;
        chunk_argmax<false>(tp + (size_t)i * V, nullptr, nullptr, v0, v1, bv, bi);
    }
    block_argmax<256>(bv, bi);
    if (tid == 0) {
        ws_pval[e * CHUNKS + c] = bv;
        ws_pidx[e * CHUNKS + c] = bi;
    }
}

// K_assemble: per request; reduce partials (L2-hot), recompute accept flags
// (L2-warm scalars), serial assembly.
__global__ void __launch_bounds__(64) k_assemble(
    const int* __restrict__ out_init, const int* __restrict__ cu,
    const int* __restrict__ draft_tok, const int* __restrict__ bonus,
    const void* __restrict__ isg_raw, const float* __restrict__ dp,
    const float* __restrict__ tp, const float* __restrict__ uni,
    const float* __restrict__ ws_pval, const int* __restrict__ ws_pidx,
    int* __restrict__ out, int B, int Sl, int V, int N)
{
    int b = blockIdx.x;
    int tid = threadIdx.x;
    int st = b ? cu[b - 1] : 0;
    int np = cu[b] - st;
    int lim = min(np, Sl);
    bool greedy = get_greedy(isg_raw, B, b);

    __shared__ int s_out[64];
    __shared__ int s_am[64];
    __shared__ unsigned char s_acc[64];
    for (int j = tid; j <= Sl; j += blockDim.x)
        s_out[j] = out_init[b * (Sl + 1) + j];

    if (greedy) {
        int nred = min(np, Sl + 1);
        for (int j = tid; j < nred; j += blockDim.x) {
            int g = min(max(st + j, 0), N - 1);
            int e = B + g;
            float bv = -FLT_MAX; int bi = INT_MAX;
            for (int c = 0; c < CHUNKS; ++c)
                amax_upd(ws_pval[e * CHUNKS + c], ws_pidx[e * CHUNKS + c], bv, bi);
            s_am[j] = bi;
        }
    } else {
        if (tid < lim) {
            int g = min(max(st + tid, 0), N - 1);
            int t = draft_tok[g];
            float dpv = dp[(size_t)g * V + t];
            float tpv = tp[(size_t)g * V + t];
            s_acc[tid] = ((dpv > 0.0f) && (tpv / dpv >= uni[g])) ? 1 : 0;
        }
    }
    __syncthreads();

    if (tid == 0) {
        if (greedy) {
            int first_mm = np;
            for (int pos = 0; pos < lim; ++pos) {
                int g = min(max(st + pos, 0), N - 1);
                if (draft_tok[g] != s_am[pos]) { first_mm = pos; break; }
            }
            int copy_len = min(first_mm + 1, np);
            for (int j = 0; j < copy_len && j <= Sl; ++j)
                s_out[j] = s_am[j];
            if (first_mm >= np && np <= Sl) s_out[np] = bonus[b];
        } else {
            int fr = Sl;
            for (int p = 0; p < lim; ++p)
                if (!s_acc[p]) { fr = p; break; }
            int acc_len = min(fr, lim);
            for (int pos = 0; pos < acc_len; ++pos) {
                int g = min(max(st + pos, 0), N - 1);
                s_out[pos] = draft_tok[g];
            }
            if (fr < lim) {
                float bv = -FLT_MAX; int bi = INT_MAX;
                for (int c = 0; c < CHUNKS; ++c)
                    amax_upd(ws_pval[b * CHUNKS + c], ws_pidx[b * CHUNKS + c],
                             bv, bi);
                s_out[fr] = bi;
            }
            if (fr >= np && np <= Sl) s_out[np] = bonus[b];
        }
    }
    __syncthreads();

    for (int j = tid; j <= Sl; j += blockDim.x)
        out[b * (Sl + 1) + j] = s_out[j];
}

extern "C" void kernel_launch(void* const* d_in, const int* in_sizes, int n_in,
                              void* d_out, int out_size, void* d_ws, size_t ws_size,
                              hipStream_t stream) {
    const int*   out_init  = (const int*)d_in[0];
    const int*   cu        = (const int*)d_in[1];
    const int*   draft_tok = (const int*)d_in[2];
    const float* dp        = (const float*)d_in[3];
    const float* tp        = (const float*)d_in[4];
    const int*   bonus     = (const int*)d_in[5];
    const float* uni       = (const float*)d_in[6];
    const float* q         = (const float*)d_in[7];
    const void*  isg_raw   = (const void*)d_in[8];
    int* out = (int*)d_out;

    int B   = in_sizes[5];          // bonus_token_ids: (B,)
    int Sp1 = out_size / B;         // S+1
    int Sl  = Sp1 - 1;
    int N   = in_sizes[2];          // draft_token_ids: (N,)
    int V   = in_sizes[3] / N;      // draft_probs: (N,V)
    int E   = B + N;

    float* ws_pval = (float*)d_ws;              // E*CHUNKS
    int*   ws_pidx = (int*)(ws_pval + E * CHUNKS); // E*CHUNKS

    k_main<<<E * CHUNKS, 256, 0, stream>>>(tp, dp, q, cu, isg_raw, draft_tok,
                                           uni, ws_pval, ws_pidx, B, Sl, V, N);
    k_assemble<<<B, 64, 0, stream>>>(out_init, cu, draft_tok, bonus, isg_raw,
                                     dp, tp, uni, ws_pval, ws_pidx, out,
                                     B, Sl, V, N);
}

// Round 6
// 21.486 us; speedup vs baseline: 1.2222x; 1.2222x over previous
//
#include <hip/hip_runtime.h>
#include <float.h>
#include <limits.h>

#define WAVE 64
#define CHUNKS 8

__device__ __forceinline__ void amax_upd(float v, int i, float& bv, int& bi) {
    if (v > bv || (v == bv && i < bi)) { bv = v; bi = i; }
}

// Block-wide argmax with first-index tie-break; result valid on thread 0.
template <int BLOCK>
__device__ __forceinline__ void block_argmax(float& bv, int& bi) {
#pragma unroll
    for (int off = 32; off > 0; off >>= 1) {
        float ov = __shfl_down(bv, off);
        int   oi = __shfl_down(bi, off);
        amax_upd(ov, oi, bv, bi);
    }
    __shared__ float sv[BLOCK / WAVE];
    __shared__ int   si[BLOCK / WAVE];
    int wid  = threadIdx.x / WAVE;
    int lane = threadIdx.x % WAVE;
    if (lane == 0) { sv[wid] = bv; si[wid] = bi; }
    __syncthreads();
    if (threadIdx.x == 0) {
        for (int w = 1; w < BLOCK / WAVE; ++w) amax_upd(sv[w], si[w], bv, bi);
    }
}

// is_greedy may be byte-packed bools or int32. Layout detect with ONE
// coalesced wave load + ballot (no serial chain): lane i loads word i of the
// first min(B,16) words (64B, in-bounds under both layouts).
// Must be called by all lanes of each wave (uniform call site).
__device__ __forceinline__ bool greedy_flag(const void* isg_raw, int B, int b) {
    int lane = threadIdx.x & (WAVE - 1);
    int nw = B < 16 ? B : 16;
    unsigned w = (lane < nw) ? ((const unsigned*)isg_raw)[lane] : 0u;
    bool is_int = !__any(w > 1u);
    int v = is_int ? ((const int*)isg_raw)[b]
                   : (int)((const unsigned char*)isg_raw)[b];
    return v != 0;
}

// Request id for row i = count of cu[t] <= i, via one coalesced load + ballot.
__device__ __forceinline__ int find_req(const int* __restrict__ cu, int B, int i) {
    int b = 0;
    for (int base = 0; base < B; base += WAVE) {
        int t = base + (threadIdx.x & (WAVE - 1));
        int c = (t < B && cu[t] <= i) ? 1 : 0;
        unsigned long long m = __ballot(c);
        b += __popcll(m);
    }
    return b;
}

// Chunk [v0,v1) argmax of tp row (greedy) or max(tp-dp,0)/q (recovery).
// 4x unrolled so each thread has 4 (or 12) independent loads in flight.
template <bool REC>
__device__ __forceinline__ void chunk_argmax(
    const float* __restrict__ tprow, const float* __restrict__ dprow,
    const float* __restrict__ qrow, int v0, int v1, float& bv, int& bi)
{
    const int tid = threadIdx.x, T = blockDim.x;
    int a0 = (v0 + 3) & ~3;
    int a1 = v1 & ~3;
    for (int v = v0 + tid; v < min(a0, v1); v += T) {
        float x = REC ? fmaxf(tprow[v] - dprow[v], 0.0f) / qrow[v] : tprow[v];
        amax_upd(x, v, bv, bi);
    }
    if (a1 > a0) {
        const float4* t4 = (const float4*)(tprow + a0);
        const float4* d4 = (const float4*)(dprow + a0);
        const float4* q4 = (const float4*)(qrow  + a0);
        int np = (a1 - a0) >> 2;
        int p = tid;
        for (; p + 3 * T < np; p += 4 * T) {
            float4 tv0 = t4[p], tv1 = t4[p + T], tv2 = t4[p + 2 * T], tv3 = t4[p + 3 * T];
            float4 pv0, pv1, pv2, pv3;
            if (REC) {
                float4 dv0 = d4[p], dv1 = d4[p + T], dv2 = d4[p + 2 * T], dv3 = d4[p + 3 * T];
                float4 qv0 = q4[p], qv1 = q4[p + T], qv2 = q4[p + 2 * T], qv3 = q4[p + 3 * T];
                pv0 = make_float4(fmaxf(tv0.x - dv0.x, 0.f) / qv0.x, fmaxf(tv0.y - dv0.y, 0.f) / qv0.y,
                                  fmaxf(tv0.z - dv0.z, 0.f) / qv0.z, fmaxf(tv0.w - dv0.w, 0.f) / qv0.w);
                pv1 = make_float4(fmaxf(tv1.x - dv1.x, 0.f) / qv1.x, fmaxf(tv1.y - dv1.y, 0.f) / qv1.y,
                                  fmaxf(tv1.z - dv1.z, 0.f) / qv1.z, fmaxf(tv1.w - dv1.w, 0.f) / qv1.w);
                pv2 = make_float4(fmaxf(tv2.x - dv2.x, 0.f) / qv2.x, fmaxf(tv2.y - dv2.y, 0.f) / qv2.y,
                                  fmaxf(tv2.z - dv2.z, 0.f) / qv2.z, fmaxf(tv2.w - dv2.w, 0.f) / qv2.w);
                pv3 = make_float4(fmaxf(tv3.x - dv3.x, 0.f) / qv3.x, fmaxf(tv3.y - dv3.y, 0.f) / qv3.y,
                                  fmaxf(tv3.z - dv3.z, 0.f) / qv3.z, fmaxf(tv3.w - dv3.w, 0.f) / qv3.w);
            } else { pv0 = tv0; pv1 = tv1; pv2 = tv2; pv3 = tv3; }
            int b0 = a0 + (p << 2), b1 = a0 + ((p + T) << 2),
                b2 = a0 + ((p + 2 * T) << 2), b3 = a0 + ((p + 3 * T) << 2);
            amax_upd(pv0.x, b0, bv, bi); amax_upd(pv0.y, b0 + 1, bv, bi);
            amax_upd(pv0.z, b0 + 2, bv, bi); amax_upd(pv0.w, b0 + 3, bv, bi);
            amax_upd(pv1.x, b1, bv, bi); amax_upd(pv1.y, b1 + 1, bv, bi);
            amax_upd(pv1.z, b1 + 2, bv, bi); amax_upd(pv1.w, b1 + 3, bv, bi);
            amax_upd(pv2.x, b2, bv, bi); amax_upd(pv2.y, b2 + 1, bv, bi);
            amax_upd(pv2.z, b2 + 2, bv, bi); amax_upd(pv2.w, b2 + 3, bv, bi);
            amax_upd(pv3.x, b3, bv, bi); amax_upd(pv3.y, b3 + 1, bv, bi);
            amax_upd(pv3.z, b3 + 2, bv, bi); amax_upd(pv3.w, b3 + 3, bv, bi);
        }
        for (; p < np; p += T) {
            float4 tv = t4[p];
            int base = a0 + (p << 2);
            if (REC) {
                float4 dv = d4[p], qv = q4[p];
                amax_upd(fmaxf(tv.x - dv.x, 0.f) / qv.x, base,     bv, bi);
                amax_upd(fmaxf(tv.y - dv.y, 0.f) / qv.y, base + 1, bv, bi);
                amax_upd(fmaxf(tv.z - dv.z, 0.f) / qv.z, base + 2, bv, bi);
                amax_upd(fmaxf(tv.w - dv.w, 0.f) / qv.w, base + 3, bv, bi);
            } else {
                amax_upd(tv.x, base, bv, bi); amax_upd(tv.y, base + 1, bv, bi);
                amax_upd(tv.z, base + 2, bv, bi); amax_upd(tv.w, base + 3, bv, bi);
            }
        }
    }
    for (int v = max(a1, a0) + tid; v < v1; v += T) {
        float x = REC ? fmaxf(tprow[v] - dprow[v], 0.0f) / qrow[v] : tprow[v];
        amax_upd(x, v, bv, bi);
    }
}

// K_main: block e*CHUNKS+c handles chunk c of entry e.
//   e in [0,B): recovery job for request e (non-greedy, first rejection).
//   e in [B,B+N): greedy argmax of tp row (e-B).
__global__ void __launch_bounds__(256) k_main(
    const float* __restrict__ tp, const float* __restrict__ dp,
    const float* __restrict__ q, const int* __restrict__ cu,
    const void* __restrict__ isg_raw, const int* __restrict__ draft_tok,
    const float* __restrict__ uni,
    float* __restrict__ ws_pval, int* __restrict__ ws_pidx,
    int B, int Sl, int V, int N)
{
    int e = blockIdx.x / CHUNKS;
    int c = blockIdx.x % CHUNKS;
    int tid = threadIdx.x;
    int v0 = (int)((long long)V * c / CHUNKS);
    int v1 = (int)((long long)V * (c + 1) / CHUNKS);
    float bv = -FLT_MAX; int bi = INT_MAX;

    if (e < B) {
        int b = e;
        if (greedy_flag(isg_raw, B, b)) return;
        int st = b ? cu[b - 1] : 0;
        int np = cu[b] - st;
        int lim = min(np, Sl);
        __shared__ unsigned char s_acc[64];
        __shared__ int s_fr;
        if (tid < lim) {
            int g = min(max(st + tid, 0), N - 1);
            int t = draft_tok[g];
            float dpv = dp[(size_t)g * V + t];
            float tpv = tp[(size_t)g * V + t];
            s_acc[tid] = ((dpv > 0.0f) && (tpv / dpv >= uni[g])) ? 1 : 0;
        }
        __syncthreads();
        if (tid == 0) {
            int fr = Sl;
            for (int p = 0; p < lim; ++p)
                if (!s_acc[p]) { fr = p; break; }
            s_fr = fr;
        }
        __syncthreads();
        int fr = s_fr;
        if (fr >= lim) return;             // no recovery needed
        int g = min(max(st + fr, 0), N - 1);
        chunk_argmax<true>(tp + (size_t)g * V, dp + (size_t)g * V,
                           q + (size_t)b * V, v0, v1, bv, bi);
    } else {
        int i = e - B;
        int b = find_req(cu, B, i);
        if (b >= B || !greedy_flag(isg_raw, B, b)) return;
        chunk_argmax<false>(tp + (size_t)i * V, nullptr, nullptr, v0, v1, bv, bi);
    }
    block_argmax<256>(bv, bi);
    if (tid == 0) {
        ws_pval[e * CHUNKS + c] = bv;
        ws_pidx[e * CHUNKS + c] = bi;
    }
}

// K_assemble: one wave (64 threads) per request. All reductions/scans via
// ballots and shuffles; gathers fully parallel across lanes.
__global__ void __launch_bounds__(64) k_assemble(
    const int* __restrict__ out_init, const int* __restrict__ cu,
    const int* __restrict__ draft_tok, const int* __restrict__ bonus,
    const void* __restrict__ isg_raw, const float* __restrict__ dp,
    const float* __restrict__ tp, const float* __restrict__ uni,
    const float* __restrict__ ws_pval, const int* __restrict__ ws_pidx,
    int* __restrict__ out, int B, int Sl, int V, int N)
{
    int b = blockIdx.x;
    int tid = threadIdx.x;
    int st = b ? cu[b - 1] : 0;
    int np = cu[b] - st;
    int lim = min(np, Sl);
    bool greedy = greedy_flag(isg_raw, B, b);

    __shared__ int s_out[64];
    for (int j = tid; j <= Sl; j += WAVE)
        s_out[j] = out_init[b * (Sl + 1) + j];
    __syncthreads();

    if (greedy) {
        // lane = row j (tid>>3) x chunk c (tid&7): parallel partial loads,
        // 8-lane butterfly reduce -> row argmax, redistribute to lanes 0..7.
        int j = tid >> 3, c = tid & 7;
        int nred = min(np, Sl + 1);
        float bv = -FLT_MAX; int bi = INT_MAX;
        if (j < nred) {
            int g = min(max(st + j, 0), N - 1);
            int e = B + g;
            bv = ws_pval[e * CHUNKS + c];
            bi = ws_pidx[e * CHUNKS + c];
        }
#pragma unroll
        for (int m = 4; m; m >>= 1) {
            float ov = __shfl_xor(bv, m);
            int   oi = __shfl_xor(bi, m);
            amax_upd(ov, oi, bv, bi);
        }
        int am_l = __shfl(bi, 8 * (tid & 7));   // lane l: argmax of row (l&7)
        int mism = 0;
        if (tid < lim) {
            int g2 = min(max(st + tid, 0), N - 1);
            mism = (draft_tok[g2] != am_l) ? 1 : 0;
        }
        unsigned long long mm = __ballot(mism);
        int first_mm = mm ? (int)__ffsll(mm) - 1 : np;
        int copy_len = min(first_mm + 1, np);
        if (tid < copy_len && tid < 8 && tid <= Sl) s_out[tid] = am_l;
        if (tid == 0 && first_mm >= np && np <= Sl) s_out[np] = bonus[b];
    } else {
        int acc = 1;
        if (tid < lim) {
            int g = min(max(st + tid, 0), N - 1);
            int t = draft_tok[g];
            float dpv = dp[(size_t)g * V + t];
            float tpv = tp[(size_t)g * V + t];
            acc = ((dpv > 0.0f) && (tpv / dpv >= uni[g])) ? 1 : 0;
        }
        unsigned long long rej = __ballot(tid < lim && !acc);
        int fr = rej ? (int)__ffsll(rej) - 1 : Sl;
        int acc_len = min(fr, lim);
        if (tid < acc_len) {
            int g = min(max(st + tid, 0), N - 1);
            s_out[tid] = draft_tok[g];
        }
        if (fr < lim) {
            float bv = -FLT_MAX; int bi = INT_MAX;
            if (tid < CHUNKS) {
                bv = ws_pval[b * CHUNKS + tid];
                bi = ws_pidx[b * CHUNKS + tid];
            }
#pragma unroll
            for (int m = 4; m; m >>= 1) {
                float ov = __shfl_xor(bv, m);
                int   oi = __shfl_xor(bi, m);
                amax_upd(ov, oi, bv, bi);
            }
            if (tid == 0) s_out[fr] = bi;
        }
        if (tid == 0 && fr >= np && np <= Sl) s_out[np] = bonus[b];
    }
    __syncthreads();

    for (int j = tid; j <= Sl; j += WAVE)
        out[b * (Sl + 1) + j] = s_out[j];
}

extern "C" void kernel_launch(void* const* d_in, const int* in_sizes, int n_in,
                              void* d_out, int out_size, void* d_ws, size_t ws_size,
                              hipStream_t stream) {
    const int*   out_init  = (const int*)d_in[0];
    const int*   cu        = (const int*)d_in[1];
    const int*   draft_tok = (const int*)d_in[2];
    const float* dp        = (const float*)d_in[3];
    const float* tp        = (const float*)d_in[4];
    const int*   bonus     = (const int*)d_in[5];
    const float* uni       = (const float*)d_in[6];
    const float* q         = (const float*)d_in[7];
    const void*  isg_raw   = (const void*)d_in[8];
    int* out = (int*)d_out;

    int B   = in_sizes[5];          // bonus_token_ids: (B,)
    int Sp1 = out_size / B;         // S+1
    int Sl  = Sp1 - 1;
    int N   = in_sizes[2];          // draft_token_ids: (N,)
    int V   = in_sizes[3] / N;      // draft_probs: (N,V)
    int E   = B + N;

    float* ws_pval = (float*)d_ws;                 // E*CHUNKS
    int*   ws_pidx = (int*)(ws_pval + E * CHUNKS); // E*CHUNKS

    k_main<<<E * CHUNKS, 256, 0, stream>>>(tp, dp, q, cu, isg_raw, draft_tok,
                                           uni, ws_pval, ws_pidx, B, Sl, V, N);
    k_assemble<<<B, 64, 0, stream>>>(out_init, cu, draft_tok, bonus, isg_raw,
                                     dp, tp, uni, ws_pval, ws_pidx, out,
                                     B, Sl, V, N);
}